// Round 10
// baseline (61.470 us; speedup 1.0000x reference)
//
#include <hip/hip_runtime.h>

// out = atoms_x - segment_mean(atoms_x, graph_batch)[graph_batch]
// graph_batch SORTED. Fused single pass. 4 independent waves/block (r9),
// each wave owns TWO consecutive 768-atom chunks, SOFTWARE-PIPELINED:
// both chunks' global loads are issued up front, so chunk B's HBM transfer
// overlaps chunk A's accumulate/halo/means/subtract phases (fills the
// memory-idle phase bubbles that capped r7/r9 at ~4.2 TB/s wall BW).
// fid/lid derived via shuffle from loaded ids (no dependent prologue loads).
// Per-thread run accumulation + LDS slot table + ballot halos (r9 paths).

static constexpr int WAVE   = 64;
static constexpr int WPB    = 4;                 // independent waves per block
static constexpr int TPB    = WAVE * WPB;
static constexpr int CPT    = 12;                // atoms per lane per chunk
static constexpr int WCHUNK = WAVE * CPT;        // 768 atoms per chunk
static constexpr int ITERS  = 2;                 // chunks per wave (pipelined)
static constexpr int SLOTS  = 96;                // id-span per chunk (exp ~20)

#define LDS_FENCE() asm volatile("s_waitcnt lgkmcnt(0)" ::: "memory")

__device__ __forceinline__ void issue_loads(
    const float* __restrict__ x, const int* __restrict__ gb,
    long long cs, long long ce, int lane,
    float* f, int* ids, bool& full) {
  long long base = cs + (long long)lane * CPT;
  full = (base + CPT <= ce);
  if (full) {
    const float4* xv = reinterpret_cast<const float4*>(x + base * 3);
#pragma unroll
    for (int j = 0; j < CPT * 3 / 4; ++j) {
      float4 v = xv[j];
      f[j * 4 + 0] = v.x; f[j * 4 + 1] = v.y;
      f[j * 4 + 2] = v.z; f[j * 4 + 3] = v.w;
    }
    const int4* gv = reinterpret_cast<const int4*>(gb + base);
#pragma unroll
    for (int j = 0; j < CPT / 4; ++j) {
      int4 g = gv[j];
      ids[j * 4 + 0] = g.x; ids[j * 4 + 1] = g.y;
      ids[j * 4 + 2] = g.z; ids[j * 4 + 3] = g.w;
    }
  }
}

__device__ __forceinline__ void process_chunk(
    const float* __restrict__ x, const int* __restrict__ gb,
    float* __restrict__ out, int n, long long cs, long long ce,
    int lane, float* __restrict__ sums,
    float* f, int* ids, bool full) {
  // fence prior iteration's LDS reads, then zero fixed slot table
  LDS_FENCE();
  {
    float4* s4 = reinterpret_cast<float4*>(sums);
    float4 z = make_float4(0.f, 0.f, 0.f, 0.f);
#pragma unroll
    for (int i = 0; i < (SLOTS + WAVE - 1) / WAVE; ++i) {
      int s = i * WAVE + lane;
      if (s < SLOTS) s4[s] = z;
    }
  }

  const bool partial = (ce - cs) < WCHUNK;  // wave-uniform (tail chunk only)
  const int fid = partial ? gb[cs] : __shfl(ids[0], 0);
  const int lid = partial ? gb[ce - 1] : __shfl(ids[CPT - 1], WAVE - 1);
  const int span = lid - fid + 1;

  if (span > SLOTS) {
    // Pathological id-sparsity; wave-uniform, never hot, correct.
    if (lane == 0) {
      long long i = cs;
      while (i < ce) {
        int id = gb[i];
        long long rs = i; while (rs > 0 && gb[rs - 1] == id) --rs;
        long long re = i; while (re < n && gb[re] == id) ++re;
        float sx = 0.f, sy = 0.f, sz = 0.f;
        for (long long k = rs; k < re; ++k) {
          sx += x[k * 3 + 0]; sy += x[k * 3 + 1]; sz += x[k * 3 + 2];
        }
        float inv = 1.f / (float)(re - rs);
        float mx = sx * inv, my = sy * inv, mz = sz * inv;
        long long we = (re < ce) ? re : ce;
        for (long long k = i; k < we; ++k) {
          out[k * 3 + 0] = x[k * 3 + 0] - mx;
          out[k * 3 + 1] = x[k * 3 + 1] - my;
          out[k * 3 + 2] = x[k * 3 + 2] - mz;
        }
        i = we;
      }
    }
    return;
  }

  const long long base = cs + (long long)lane * CPT;

  if (full) {
    // ---- per-thread run accumulation, flush at id boundaries ----
    int cur = ids[0];
    float sx = 0.f, sy = 0.f, sz = 0.f, sc = 0.f;
#pragma unroll
    for (int j = 0; j < CPT; ++j) {
      if (ids[j] != cur) {
        int s = (cur - fid) * 4;
        atomicAdd(&sums[s + 0], sx); atomicAdd(&sums[s + 1], sy);
        atomicAdd(&sums[s + 2], sz); atomicAdd(&sums[s + 3], sc);
        cur = ids[j]; sx = sy = sz = sc = 0.f;
      }
      sx += f[j * 3 + 0]; sy += f[j * 3 + 1]; sz += f[j * 3 + 2]; sc += 1.f;
    }
    {
      int s = (cur - fid) * 4;
      atomicAdd(&sums[s + 0], sx); atomicAdd(&sums[s + 1], sy);
      atomicAdd(&sums[s + 2], sz); atomicAdd(&sums[s + 3], sc);
    }
  } else if (base < ce) {
    for (long long i = base; i < ce; ++i) {
      int s = (gb[i] - fid) * 4;
      atomicAdd(&sums[s + 0], x[i * 3 + 0]);
      atomicAdd(&sums[s + 1], x[i * 3 + 1]);
      atomicAdd(&sums[s + 2], x[i * 3 + 2]);
      atomicAdd(&sums[s + 3], 1.f);
    }
  }

  // ---- halos: 64-lane ballot-stepped probes ----
  if (cs > 0) {
    float hx = 0.f, hy = 0.f, hz = 0.f, hc = 0.f;
    long long off = 1 + lane;
    for (;;) {
      long long i = cs - off;
      bool m = (i >= 0) && (gb[i] == fid);
      if (m) {
        hx += x[i * 3 + 0]; hy += x[i * 3 + 1]; hz += x[i * 3 + 2]; hc += 1.f;
      }
      if (__popcll(__ballot(m)) < WAVE) break;
      off += WAVE;
    }
#pragma unroll
    for (int d = 1; d < 64; d <<= 1) {
      hx += __shfl_xor(hx, d); hy += __shfl_xor(hy, d);
      hz += __shfl_xor(hz, d); hc += __shfl_xor(hc, d);
    }
    if (lane == 0 && hc > 0.f) {
      atomicAdd(&sums[0], hx); atomicAdd(&sums[1], hy);
      atomicAdd(&sums[2], hz); atomicAdd(&sums[3], hc);
    }
  }
  if (ce < (long long)n) {
    float hx = 0.f, hy = 0.f, hz = 0.f, hc = 0.f;
    long long off = (long long)lane;
    for (;;) {
      long long i = ce + off;
      bool m = (i < (long long)n) && (gb[i] == lid);
      if (m) {
        hx += x[i * 3 + 0]; hy += x[i * 3 + 1]; hz += x[i * 3 + 2]; hc += 1.f;
      }
      if (__popcll(__ballot(m)) < WAVE) break;
      off += WAVE;
    }
#pragma unroll
    for (int d = 1; d < 64; d <<= 1) {
      hx += __shfl_xor(hx, d); hy += __shfl_xor(hy, d);
      hz += __shfl_xor(hz, d); hc += __shfl_xor(hc, d);
    }
    if (lane == 0 && hc > 0.f) {
      int s = (lid - fid) * 4;
      atomicAdd(&sums[s + 0], hx); atomicAdd(&sums[s + 1], hy);
      atomicAdd(&sums[s + 2], hz); atomicAdd(&sums[s + 3], hc);
    }
  }
  LDS_FENCE();

  // ---- sums -> means ----
  for (int s = lane; s < span; s += WAVE) {
    float c = sums[s * 4 + 3];
    if (c > 0.f) {
      float inv = 1.f / c;
      sums[s * 4 + 0] *= inv; sums[s * 4 + 1] *= inv; sums[s * 4 + 2] *= inv;
    }
  }
  LDS_FENCE();

  // ---- subtract + float4 stores (fire-and-forget) ----
  if (full) {
#pragma unroll
    for (int j = 0; j < CPT; ++j) {
      int s = (ids[j] - fid) * 4;
      f[j * 3 + 0] -= sums[s + 0];
      f[j * 3 + 1] -= sums[s + 1];
      f[j * 3 + 2] -= sums[s + 2];
    }
    float4* ov = reinterpret_cast<float4*>(out + base * 3);
#pragma unroll
    for (int j = 0; j < CPT * 3 / 4; ++j)
      ov[j] = make_float4(f[j * 4 + 0], f[j * 4 + 1],
                          f[j * 4 + 2], f[j * 4 + 3]);
  } else if (base < ce) {
    for (long long i = base; i < ce; ++i) {
      int s = (gb[i] - fid) * 4;
      out[i * 3 + 0] = x[i * 3 + 0] - sums[s + 0];
      out[i * 3 + 1] = x[i * 3 + 1] - sums[s + 1];
      out[i * 3 + 2] = x[i * 3 + 2] - sums[s + 2];
    }
  }
}

__global__ __launch_bounds__(TPB) void fused_center_kernel(
    const float* __restrict__ x, const int* __restrict__ gb,
    float* __restrict__ out, int n, int nchunks) {
  __shared__ float sums_all[WPB][SLOTS * 4];  // private per-wave tables

  const int w = threadIdx.x >> 6;
  const int lane = threadIdx.x & 63;
  float* sums = sums_all[w];

  const long long g = (long long)blockIdx.x * WPB + w;  // global wave id
  const long long c0 = g * ITERS;
  const long long c1 = c0 + 1;
  if (c0 >= nchunks) return;  // idle wave; no barriers anywhere -> safe

  const long long cs0 = c0 * WCHUNK;
  const long long ce0 = (cs0 + WCHUNK < (long long)n) ? cs0 + WCHUNK : (long long)n;
  const bool hasB = (c1 < nchunks);
  const long long cs1 = c1 * WCHUNK;
  const long long ce1 = (cs1 + WCHUNK < (long long)n) ? cs1 + WCHUNK : (long long)n;

  float fA[CPT * 3]; int idsA[CPT]; bool fullA = false;
  float fB[CPT * 3]; int idsB[CPT]; bool fullB = false;

  // issue BOTH chunks' loads up front: B's transfer hides under A's phases
  issue_loads(x, gb, cs0, ce0, lane, fA, idsA, fullA);
  if (hasB) issue_loads(x, gb, cs1, ce1, lane, fB, idsB, fullB);

  process_chunk(x, gb, out, n, cs0, ce0, lane, sums, fA, idsA, fullA);
  if (hasB)
    process_chunk(x, gb, out, n, cs1, ce1, lane, sums, fB, idsB, fullB);
}

extern "C" void kernel_launch(void* const* d_in, const int* in_sizes, int n_in,
                              void* d_out, int out_size, void* d_ws, size_t ws_size,
                              hipStream_t stream) {
  const float* x = (const float*)d_in[0];
  const int* gb = (const int*)d_in[1];
  float* out = (float*)d_out;
  const int n = in_sizes[0] / 3;  // atoms

  int nchunks = (int)(((long long)n + WCHUNK - 1) / WCHUNK);
  long long nwaves = (nchunks + ITERS - 1) / ITERS;
  int blocks = (int)((nwaves + WPB - 1) / WPB);
  fused_center_kernel<<<blocks, TPB, 0, stream>>>(x, gb, out, n, nchunks);
}

// Round 11
// 60.970 us; speedup vs baseline: 1.0082x; 1.0082x over previous
//
#include <hip/hip_runtime.h>

// out = atoms_x - segment_mean(atoms_x, graph_batch)[graph_batch]
// graph_batch SORTED. Fused single pass, 1 wave/WG.
// ALL global access is DENSE (lane-interleaved flat float4/int4: 16 cache
// lines per wave instruction, vs 64 for chunked ownership -- the r7/r9
// limiter: ~1.4M line-transactions/CU ~= 45us at 1 line/cyc matches 53us).
// A padded LDS bounce (group stride 216B/72B, >=16-bank spread) repacks
// interleaved->lane-contiguous so r9's cheap per-thread run accumulation
// still works. Subtract is done flat from the live dense registers.

static constexpr int WAVE   = 64;
static constexpr int TPB    = 64;          // one wave per WG
static constexpr int CPT    = 8;           // atoms per lane
static constexpr int WCHUNK = WAVE * CPT;  // 512 atoms per WG
static constexpr int SLOTS  = 96;          // id-span per chunk (exp ~14)
static constexpr int NGRP   = WCHUNK / 16; // 32 groups of 16 atoms
static constexpr int XGRP   = 216;         // B per group: 16*12 + 24 pad
static constexpr int IGRP   = 72;          // B per group: 16*4  + 8 pad

#define LDS_FENCE() asm volatile("s_waitcnt lgkmcnt(0)" ::: "memory")

__device__ void serial_fallback(const float* __restrict__ x,
                                const int* __restrict__ gb,
                                float* __restrict__ out, int n,
                                long long cs, long long ce, int lane) {
  // Pathological id-sparsity; wave-uniform, never hot, correct.
  if (lane != 0) return;
  long long i = cs;
  while (i < ce) {
    int id = gb[i];
    long long rs = i; while (rs > 0 && gb[rs - 1] == id) --rs;
    long long re = i; while (re < n && gb[re] == id) ++re;
    float sx = 0.f, sy = 0.f, sz = 0.f;
    for (long long k = rs; k < re; ++k) {
      sx += x[k * 3 + 0]; sy += x[k * 3 + 1]; sz += x[k * 3 + 2];
    }
    float inv = 1.f / (float)(re - rs);
    float mx = sx * inv, my = sy * inv, mz = sz * inv;
    long long we = (re < ce) ? re : ce;
    for (long long k = i; k < we; ++k) {
      out[k * 3 + 0] = x[k * 3 + 0] - mx;
      out[k * 3 + 1] = x[k * 3 + 1] - my;
      out[k * 3 + 2] = x[k * 3 + 2] - mz;
    }
    i = we;
  }
}

__global__ __launch_bounds__(TPB) void fused_center_kernel(
    const float* __restrict__ x, const int* __restrict__ gb,
    float* __restrict__ out, int n) {
  __shared__ alignas(16) char xbuf[NGRP * XGRP];   // 6912 B
  __shared__ alignas(16) char ibuf[NGRP * IGRP];   // 2304 B
  __shared__ alignas(16) float sums[SLOTS * 4];    // 1536 B

  const int lane = threadIdx.x;
  const long long cs = (long long)blockIdx.x * WCHUNK;
  const long long ce = (cs + WCHUNK < (long long)n) ? cs + WCHUNK : (long long)n;

  if (ce - cs < WCHUNK) {
    // ---- tail chunk (at most one per grid): interleaved scalar ----
    const int fid = gb[cs];
    const int lid = gb[ce - 1];
    const int span = lid - fid + 1;
    if (span > SLOTS) { serial_fallback(x, gb, out, n, cs, ce, lane); return; }
    for (int s = lane; s < span * 4; s += WAVE) sums[s] = 0.f;
    LDS_FENCE();
    for (long long i = cs + lane; i < ce; i += WAVE) {
      int s = (gb[i] - fid) * 4;
      atomicAdd(&sums[s + 0], x[i * 3 + 0]);
      atomicAdd(&sums[s + 1], x[i * 3 + 1]);
      atomicAdd(&sums[s + 2], x[i * 3 + 2]);
      atomicAdd(&sums[s + 3], 1.f);
    }
    if (cs > 0) {  // front halo (ce == n here, so no back halo)
      float hx = 0.f, hy = 0.f, hz = 0.f, hc = 0.f;
      long long off = 1 + lane;
      for (;;) {
        long long i = cs - off;
        bool m = (i >= 0) && (gb[i] == fid);
        if (m) { hx += x[i*3+0]; hy += x[i*3+1]; hz += x[i*3+2]; hc += 1.f; }
        if (__popcll(__ballot(m)) < WAVE) break;
        off += WAVE;
      }
#pragma unroll
      for (int d = 1; d < 64; d <<= 1) {
        hx += __shfl_xor(hx, d); hy += __shfl_xor(hy, d);
        hz += __shfl_xor(hz, d); hc += __shfl_xor(hc, d);
      }
      if (lane == 0 && hc > 0.f) {
        atomicAdd(&sums[0], hx); atomicAdd(&sums[1], hy);
        atomicAdd(&sums[2], hz); atomicAdd(&sums[3], hc);
      }
    }
    LDS_FENCE();
    for (int s = lane; s < span; s += WAVE) {
      float c = sums[s * 4 + 3];
      if (c > 0.f) {
        float inv = 1.f / c;
        sums[s*4+0] *= inv; sums[s*4+1] *= inv; sums[s*4+2] *= inv;
      }
    }
    LDS_FENCE();
    for (long long i = cs + lane; i < ce; i += WAVE) {
      int s = (gb[i] - fid) * 4;
      out[i * 3 + 0] = x[i * 3 + 0] - sums[s + 0];
      out[i * 3 + 1] = x[i * 3 + 1] - sums[s + 1];
      out[i * 3 + 2] = x[i * 3 + 2] - sums[s + 2];
    }
    return;
  }

  // ---- dense global loads (16 lines / wave instruction) ----
  float4 xr[6];
  const float4* xv = reinterpret_cast<const float4*>(x + cs * 3);
#pragma unroll
  for (int j = 0; j < 6; ++j) xr[j] = xv[j * WAVE + lane];
  int4 gr[2];
  const int4* gv = reinterpret_cast<const int4*>(gb + cs);
#pragma unroll
  for (int j = 0; j < 2; ++j) gr[j] = gv[j * WAVE + lane];

  // ---- stage to padded LDS (interleaved -> lane-contiguous readable) ----
#pragma unroll
  for (int j = 0; j < 6; ++j) {
    int i = j * WAVE + lane;
    int k0 = 2 * i, k1 = 2 * i + 1;   // float2 indices (24 per 16-atom group)
    *reinterpret_cast<float2*>(xbuf + (k0 / 24) * XGRP + (k0 % 24) * 8) =
        make_float2(xr[j].x, xr[j].y);
    *reinterpret_cast<float2*>(xbuf + (k1 / 24) * XGRP + (k1 % 24) * 8) =
        make_float2(xr[j].z, xr[j].w);
  }
#pragma unroll
  for (int j = 0; j < 2; ++j) {
    int i = j * WAVE + lane;
    int k0 = 2 * i, k1 = 2 * i + 1;   // int2 indices (8 per 16-atom group)
    *reinterpret_cast<int2*>(ibuf + (k0 / 8) * IGRP + (k0 % 8) * 8) =
        make_int2(gr[j].x, gr[j].y);
    *reinterpret_cast<int2*>(ibuf + (k1 / 8) * IGRP + (k1 % 8) * 8) =
        make_int2(gr[j].z, gr[j].w);
  }
  {
    float4 z = make_float4(0.f, 0.f, 0.f, 0.f);
    reinterpret_cast<float4*>(sums)[lane] = z;           // slots 0..63
    if (lane < SLOTS - WAVE) reinterpret_cast<float4*>(sums)[WAVE + lane] = z;
  }
  LDS_FENCE();

  // ---- per-thread contiguous ids from LDS ----
  int idk[CPT];
  const int a0 = lane * CPT;
#pragma unroll
  for (int j = 0; j < CPT; ++j) {
    int a = a0 + j;
    idk[j] = *reinterpret_cast<const int*>(ibuf + (a / 16) * IGRP + (a % 16) * 4);
  }
  const int fid = __shfl(idk[0], 0);
  const int lid = __shfl(idk[CPT - 1], WAVE - 1);
  const int span = lid - fid + 1;
  if (span > SLOTS) { serial_fallback(x, gb, out, n, cs, ce, lane); return; }

  // ---- per-thread run accumulation (x read lane-contiguous from LDS) ----
  {
    int cur = idk[0];
    float sx = 0.f, sy = 0.f, sz = 0.f, sc = 0.f;
#pragma unroll
    for (int j = 0; j < CPT; ++j) {
      if (idk[j] != cur) {
        int s = (cur - fid) * 4;
        atomicAdd(&sums[s + 0], sx); atomicAdd(&sums[s + 1], sy);
        atomicAdd(&sums[s + 2], sz); atomicAdd(&sums[s + 3], sc);
        cur = idk[j]; sx = sy = sz = sc = 0.f;
      }
      int a = a0 + j;
      const char* p = xbuf + (a / 16) * XGRP + (a % 16) * 12;
      sx += *reinterpret_cast<const float*>(p + 0);
      sy += *reinterpret_cast<const float*>(p + 4);
      sz += *reinterpret_cast<const float*>(p + 8);
      sc += 1.f;
    }
    int s = (cur - fid) * 4;
    atomicAdd(&sums[s + 0], sx); atomicAdd(&sums[s + 1], sy);
    atomicAdd(&sums[s + 2], sz); atomicAdd(&sums[s + 3], sc);
  }

  // ---- halos: ballot-stepped probes complete the edge molecules ----
  if (cs > 0) {
    float hx = 0.f, hy = 0.f, hz = 0.f, hc = 0.f;
    long long off = 1 + lane;
    for (;;) {
      long long i = cs - off;
      bool m = (i >= 0) && (gb[i] == fid);
      if (m) { hx += x[i*3+0]; hy += x[i*3+1]; hz += x[i*3+2]; hc += 1.f; }
      if (__popcll(__ballot(m)) < WAVE) break;
      off += WAVE;
    }
#pragma unroll
    for (int d = 1; d < 64; d <<= 1) {
      hx += __shfl_xor(hx, d); hy += __shfl_xor(hy, d);
      hz += __shfl_xor(hz, d); hc += __shfl_xor(hc, d);
    }
    if (lane == 0 && hc > 0.f) {
      atomicAdd(&sums[0], hx); atomicAdd(&sums[1], hy);
      atomicAdd(&sums[2], hz); atomicAdd(&sums[3], hc);
    }
  }
  if (ce < (long long)n) {
    float hx = 0.f, hy = 0.f, hz = 0.f, hc = 0.f;
    long long off = (long long)lane;
    for (;;) {
      long long i = ce + off;
      bool m = (i < (long long)n) && (gb[i] == lid);
      if (m) { hx += x[i*3+0]; hy += x[i*3+1]; hz += x[i*3+2]; hc += 1.f; }
      if (__popcll(__ballot(m)) < WAVE) break;
      off += WAVE;
    }
#pragma unroll
    for (int d = 1; d < 64; d <<= 1) {
      hx += __shfl_xor(hx, d); hy += __shfl_xor(hy, d);
      hz += __shfl_xor(hz, d); hc += __shfl_xor(hc, d);
    }
    if (lane == 0 && hc > 0.f) {
      int s = (lid - fid) * 4;
      atomicAdd(&sums[s + 0], hx); atomicAdd(&sums[s + 1], hy);
      atomicAdd(&sums[s + 2], hz); atomicAdd(&sums[s + 3], hc);
    }
  }
  LDS_FENCE();

  // ---- sums -> means ----
  for (int s = lane; s < span; s += WAVE) {
    float c = sums[s * 4 + 3];
    if (c > 0.f) {
      float inv = 1.f / c;
      sums[s*4+0] *= inv; sums[s*4+1] *= inv; sums[s*4+2] *= inv;
    }
  }
  LDS_FENCE();

  // ---- flat subtract from live dense registers + dense stores ----
  float4* ov = reinterpret_cast<float4*>(out + cs * 3);
#pragma unroll
  for (int j = 0; j < 6; ++j) {
    int i = j * WAVE + lane;
    int e = 4 * i;
    float4 o;
#pragma unroll
    for (int c = 0; c < 4; ++c) {
      int ee = e + c;
      int atom = (int)(((unsigned)ee * 0xAAABu) >> 17);  // ee/3, ee < 32768
      int comp = ee - atom * 3;
      int id = *reinterpret_cast<const int*>(
          ibuf + (atom / 16) * IGRP + (atom % 16) * 4);
      float m = sums[(id - fid) * 4 + comp];
      float v = (c == 0) ? xr[j].x : (c == 1) ? xr[j].y
              : (c == 2) ? xr[j].z : xr[j].w;
      if (c == 0) o.x = v - m;
      else if (c == 1) o.y = v - m;
      else if (c == 2) o.z = v - m;
      else o.w = v - m;
    }
    ov[i] = o;
  }
}

extern "C" void kernel_launch(void* const* d_in, const int* in_sizes, int n_in,
                              void* d_out, int out_size, void* d_ws, size_t ws_size,
                              hipStream_t stream) {
  const float* x = (const float*)d_in[0];
  const int* gb = (const int*)d_in[1];
  float* out = (float*)d_out;
  const int n = in_sizes[0] / 3;  // atoms

  int blocks = (int)(((long long)n + WCHUNK - 1) / WCHUNK);
  fused_center_kernel<<<blocks, TPB, 0, stream>>>(x, gb, out, n);
}